// Round 1
// baseline (4569.506 us; speedup 1.0000x reference)
//
#include <hip/hip_runtime.h>
#include <stdint.h>

#define DEVI __device__ __forceinline__

#define S_TOT 261888
#define NIMG  2
#define SCLD  4.135166556742356   // log(1000/16)

// ---------------- constant tables (all compile-time) ----------------
__constant__ int    c_S[5]    = {196608, 49152, 12288, 3072, 768};
__constant__ int    c_loff[5] = {0, 196608, 245760, 258048, 261120};
__constant__ int    c_K[5]    = {1000, 1000, 1000, 1000, 768};
__constant__ int    c_Wl[5]   = {256, 128, 64, 32, 16};
__constant__ int    c_str[5]  = {4, 8, 16, 32, 64};
__constant__ double c_sz[5]   = {32.0, 64.0, 128.0, 256.0, 512.0};
__constant__ double c_rat[3]  = {0.5, 1.0, 2.0};

// order-preserving float<->uint key (ascending key == ascending float)
DEVI unsigned key_of(float f) {
  unsigned u = __float_as_uint(f);
  return (u & 0x80000000u) ? ~u : (u | 0x80000000u);
}
DEVI float key_dec(unsigned k) {
  unsigned u = (k & 0x80000000u) ? (k & 0x7fffffffu) : ~k;
  return __uint_as_float(u);
}

// ---------------- kernel 1: weight transpose w[co][k] -> wT[k][co] ----------------
__global__ void transpose_w(const float* __restrict__ w, float* __restrict__ wT) {
  int k  = blockIdx.x;   // 0..2303  (ci*9 + ky*3 + kx)
  int co = threadIdx.x;  // 0..255
  wT[k * 256 + co] = w[co * 2304 + k];
}

// ---------------- kernel 2: fused conv3x3+bias+relu then 1x1 obj/delta ----------------
// block = 512 thr (8 waves). lanes = 64 pixels (16x4 tile), wave w owns cout [32w,32w+32)
__global__ __launch_bounds__(512) void conv_fused(
    const float* __restrict__ x, const float* __restrict__ wT,
    const float* __restrict__ cb, const float* __restrict__ ow,
    const float* __restrict__ ob, const float* __restrict__ dwt,
    const float* __restrict__ db, float* __restrict__ logits,
    float* __restrict__ deltas, int H, int W, int loff)
{
  __shared__ float lds[7680];   // 30 KB: patch (3456 floats) then reduce buf (7680)
  const int tid = threadIdx.x;
  const int n = blockIdx.y;
  const int tilesx = W >> 4;
  const int tx = blockIdx.x % tilesx, ty = blockIdx.x / tilesx;
  const int px0 = tx << 4, py0 = ty << 2;
  const int lane = tid & 63, wv = tid >> 6;
  const int px = lane & 15, py = lane >> 4;
  const int co0 = __builtin_amdgcn_readfirstlane(wv << 5);   // wave-uniform -> s_load path
  const float* xin = x + (size_t)n * 256 * H * W;

  float acc[32];
#pragma unroll
  for (int i = 0; i < 32; ++i) acc[i] = 0.f;

  for (int ch = 0; ch < 8; ++ch) {          // 8 chunks of 32 input channels
    const int ci0 = ch << 5;
    __syncthreads();
    // stage input patch 32ci x 6 x 18 (zero-padded halo)
    for (int tt = tid; tt < 32 * 108; tt += 512) {
      int ci = tt / 108, rem = tt % 108;
      int ry = rem / 18, rx = rem % 18;
      int gy = py0 + ry - 1, gx = px0 + rx - 1;
      float v = 0.f;
      if (gy >= 0 && gy < H && gx >= 0 && gx < W)
        v = xin[((size_t)(ci0 + ci) * H + gy) * W + gx];
      lds[tt] = v;
    }
    __syncthreads();
#pragma unroll 1
    for (int cc = 0; cc < 32; ++cc) {
      const int pb = cc * 108 + py * 18 + px;
      float pv[9];
#pragma unroll
      for (int ky = 0; ky < 3; ++ky)
#pragma unroll
        for (int kx = 0; kx < 3; ++kx)
          pv[ky * 3 + kx] = lds[pb + ky * 18 + kx];
      const float* wr = wT + ((size_t)(ci0 + cc) * 9) * 256 + co0;  // uniform addr
#pragma unroll
      for (int j = 0; j < 9; ++j) {
        const float p = pv[j];
#pragma unroll
        for (int i = 0; i < 32; ++i)
          acc[i] = fmaf(wr[j * 256 + i], p, acc[i]);
      }
    }
  }

  // epilogue: bias+relu, then partial 1x1 convs (3 obj + 12 delta) over this wave's 32 ch
  float part[15];
#pragma unroll
  for (int f = 0; f < 15; ++f) part[f] = 0.f;
#pragma unroll
  for (int i = 0; i < 32; ++i) {
    float t = fmaxf(acc[i] + cb[co0 + i], 0.f);
#pragma unroll
    for (int f = 0; f < 3; ++f)  part[f]     = fmaf(t, ow[f * 256 + co0 + i],  part[f]);
#pragma unroll
    for (int f = 0; f < 12; ++f) part[3 + f] = fmaf(t, dwt[f * 256 + co0 + i], part[3 + f]);
  }
  __syncthreads();
#pragma unroll
  for (int f = 0; f < 15; ++f) lds[wv * 960 + f * 64 + lane] = part[f];
  __syncthreads();
  for (int tt = tid; tt < 960; tt += 512) {
    float s = 0.f;
#pragma unroll
    for (int w2 = 0; w2 < 8; ++w2) s += lds[w2 * 960 + tt];   // fixed order: deterministic
    int f = tt >> 6, p = tt & 63;
    int gx = px0 + (p & 15), gy = py0 + (p >> 4);
    int cell = gy * W + gx;
    if (f < 3) {
      logits[(size_t)n * S_TOT + loff + cell * 3 + f] = s + ob[f];
    } else {
      int chn = f - 3, a = chn >> 2, c = chn & 3;
      deltas[(((size_t)n * S_TOT + loff + cell * 3 + a) << 2) + c] = s + db[chn];
    }
  }
}

// ---------------- kernel 3: exact top-K + box decode per (image, level) ----------------
__global__ __launch_bounds__(1024) void topk_kernel(
    const float* __restrict__ logits, const float* __restrict__ deltas,
    float* __restrict__ selscore, float* __restrict__ selbox,
    unsigned* __restrict__ selvalid)
{
  const int tid = threadIdx.x;
  const int nl = blockIdx.x, n = nl / 5, l = nl % 5;
  const int Sl = c_S[l], loff = c_loff[l], Kl = c_K[l], Wl = c_Wl[l], strl = c_str[l];
  const float* sc = logits + (size_t)n * S_TOT + loff;

  __shared__ unsigned hist[256];
  __shared__ unsigned sh_prefix, sh_need, s_base, s_cb;
  __shared__ unsigned waveTot[16], waveOff[16];
  __shared__ unsigned long long sortbuf[1024];

  // phase 1: 4-pass radix histogram -> exact Kl-th largest key
  unsigned prefix = 0, need = (unsigned)Kl;
  for (int p = 0; p < 4; ++p) {
    for (int i = tid; i < 256; i += 1024) hist[i] = 0;
    __syncthreads();
    const int shift = 24 - p * 8;
    for (int i = tid; i < Sl; i += 1024) {
      unsigned k = key_of(sc[i]);
      if (p == 0 || (k >> (shift + 8)) == prefix)
        atomicAdd(&hist[(k >> shift) & 255u], 1u);
    }
    __syncthreads();
    if (tid == 0) {
      unsigned cum = 0;
      for (int b = 255; b >= 0; --b) {
        unsigned c = hist[b];
        if (cum + c >= need) { sh_prefix = (prefix << 8) | (unsigned)b; sh_need = need - cum; break; }
        cum += c;
      }
    }
    __syncthreads();
    prefix = sh_prefix; need = sh_need;
    __syncthreads();
  }
  const unsigned Tkey = prefix;

  // phase 2: stable compaction (strictly-greater, then equals capped) -> exactly Kl entries
  if (tid == 0) s_base = 0;
  __syncthreads();
  for (int pass = 0; pass < 2; ++pass) {
    for (int st = 0; st < Sl; st += 1024) {
      const int i = st + tid;
      bool flag = false; unsigned k = 0;
      if (i < Sl) {
        k = key_of(sc[i]);
        flag = (pass == 0) ? (k > Tkey) : (k == Tkey);
      }
      unsigned long long m = __ballot(flag);
      const int lane = tid & 63, w = tid >> 6;
      unsigned mypre = (unsigned)__popcll(m & ((1ull << lane) - 1ull));
      if (lane == 0) waveTot[w] = (unsigned)__popcll(m);
      __syncthreads();
      if (tid == 0) {
        unsigned ss = 0;
        for (int q = 0; q < 16; ++q) { waveOff[q] = ss; ss += waveTot[q]; }
        s_cb = s_base; s_base += ss;
      }
      __syncthreads();
      if (flag) {
        unsigned pos = s_cb + waveOff[w] + mypre;
        if (pos < (unsigned)Kl)
          sortbuf[pos] = (((unsigned long long)k) << 32) |
                         (unsigned long long)(0xFFFFFFFFu - (unsigned)i);
      }
      __syncthreads();
    }
  }
  if (tid >= Kl) sortbuf[tid] = (unsigned long long)(0xFFFFFFFFu - (unsigned)tid); // pads: key 0
  __syncthreads();

  // phase 3: bitonic sort of 1024 u64, descending (key desc, idx asc via ~idx)
  for (int k2 = 2; k2 <= 1024; k2 <<= 1) {
    for (int j = k2 >> 1; j > 0; j >>= 1) {
      const int i = tid, ixj = i ^ j;
      if (ixj > i) {
        unsigned long long a = sortbuf[i], b = sortbuf[ixj];
        const bool desc = (i & k2) == 0;
        if (desc ? (a < b) : (a > b)) { sortbuf[i] = b; sortbuf[ixj] = a; }
      }
      __syncthreads();
    }
  }

  // phase 4: decode boxes (anchors in f64 to bit-match np reference)
  const int r = tid;
  const int o = nl * 1024 + r;
  if (r < Kl) {
    unsigned long long v = sortbuf[r];
    unsigned k = (unsigned)(v >> 32);
    unsigned ai = 0xFFFFFFFFu - (unsigned)(v & 0xFFFFFFFFull);
    float score = key_dec(k);
    int cell = (int)(ai / 3u), a = (int)(ai % 3u);
    int xg = cell % Wl, yg = cell / Wl;
    double rr = c_rat[a], sz = c_sz[l];
    double wsd = sqrt(sz * sz / rr);
    double hw = 0.5 * wsd, hh = 0.5 * wsd * rr;
    double xs = (double)(xg * strl), ys = (double)(yg * strl);
    float a0 = (float)(xs - hw), a1 = (float)(ys - hh);
    float a2 = (float)(xs + hw), a3 = (float)(ys + hh);
    const float* dp = deltas + (((size_t)n * S_TOT + loff + ai) << 2);
    float dx = dp[0], dy = dp[1], dw_ = dp[2], dh_ = dp[3];
    float aw = a2 - a0, ah = a3 - a1;
    float cx = a0 + 0.5f * aw, cy = a1 + 0.5f * ah;
    dw_ = fminf(dw_, (float)SCLD); dh_ = fminf(dh_, (float)SCLD);
    float pcx = dx * aw + cx, pcy = dy * ah + cy;
    float pw = expf(dw_) * aw, ph = expf(dh_) * ah;
    float b0 = fminf(fmaxf(pcx - 0.5f * pw, 0.f), 1024.f);
    float b1 = fminf(fmaxf(pcy - 0.5f * ph, 0.f), 1024.f);
    float b2 = fminf(fmaxf(pcx + 0.5f * pw, 0.f), 1024.f);
    float b3 = fminf(fmaxf(pcy + 0.5f * ph, 0.f), 1024.f);
    unsigned valid = ((b2 - b0) > 0.f && (b3 - b1) > 0.f) ? 1u : 0u;
    selscore[o] = score;
    selbox[o * 4 + 0] = b0; selbox[o * 4 + 1] = b1;
    selbox[o * 4 + 2] = b2; selbox[o * 4 + 3] = b3;
    selvalid[o] = valid;
  } else {
    selscore[o] = -1e9f;
    selbox[o * 4 + 0] = 0.f; selbox[o * 4 + 1] = 0.f;
    selbox[o * 4 + 2] = 0.f; selbox[o * 4 + 3] = 0.f;
    selvalid[o] = 0u;
  }
}

// ---------------- kernel 4: NMS suppression bitmask matrix ----------------
__global__ __launch_bounds__(256) void nms_sup(
    const float* __restrict__ selbox, unsigned long long* __restrict__ sup)
{
  int gid = blockIdx.x * 256 + threadIdx.x;  // 10 * 1024 * 16
  int w = gid & 15, i = (gid >> 4) & 1023, nl = gid >> 14;
  if (nl >= 10) return;
  int l = nl % 5, Kl = c_K[l];
  unsigned long long bits = 0;
  if (i < Kl) {
    const float* bi = selbox + (size_t)(nl * 1024 + i) * 4;
    float x0 = bi[0], y0 = bi[1], x1 = bi[2], y1 = bi[3];
    float ar = (x1 - x0) * (y1 - y0);
    int jlo = w * 64; if (jlo < i + 1) jlo = i + 1;
    int jhi = w * 64 + 64; if (jhi > Kl) jhi = Kl;
    for (int j = jlo; j < jhi; ++j) {
      const float* bj = selbox + (size_t)(nl * 1024 + j) * 4;
      float u0 = fmaxf(x0, bj[0]), v0 = fmaxf(y0, bj[1]);
      float u1 = fminf(x1, bj[2]), v1 = fminf(y1, bj[3]);
      float iw = fmaxf(u1 - u0, 0.f), ih = fmaxf(v1 - v0, 0.f);
      float inter = iw * ih;
      float aj = (bj[2] - bj[0]) * (bj[3] - bj[1]);
      float iou = inter / fmaxf(ar + aj - inter, 1e-9f);
      if (iou > 0.7f) bits |= 1ull << (j - w * 64);
    }
  }
  sup[(size_t)(nl * 1024 + i) * 16 + w] = bits;
}

// ---------------- kernel 5: sequential greedy NMS reduce (1 wave / (n,l)) ----------------
__global__ __launch_bounds__(64) void nms_reduce(
    const unsigned* __restrict__ selvalid, const unsigned long long* __restrict__ sup,
    const float* __restrict__ selscore, float* __restrict__ scnms)
{
  const int nl = blockIdx.x, tid = threadIdx.x;
  const int l = nl % 5, Kl = c_K[l];
  unsigned long long keep = 0;
  if (tid < 16) {
    for (int t = 0; t < 64; ++t) {
      int r = tid * 64 + t;
      if (r < Kl && selvalid[nl * 1024 + r]) keep |= 1ull << t;
    }
  }
  const unsigned long long* srow = sup + (size_t)nl * 1024 * 16;
  unsigned long long rowA = (tid < 16) ? srow[(size_t)0 * 16 + tid] : 0;
  unsigned long long rowB = (tid < 16 && Kl > 1) ? srow[(size_t)1 * 16 + tid] : 0;
  for (int i = 0; i < Kl; i += 2) {   // Kl is even (1000 / 768)
    unsigned long long kw = __shfl(keep, i >> 6);
    unsigned long long cur = rowA;
    rowA = (tid < 16 && i + 2 < Kl) ? srow[(size_t)(i + 2) * 16 + tid] : 0;
    if (((kw >> (i & 63)) & 1ull) && tid < 16) keep &= ~cur;
    kw = __shfl(keep, (i + 1) >> 6);
    cur = rowB;
    rowB = (tid < 16 && i + 3 < Kl) ? srow[(size_t)(i + 3) * 16 + tid] : 0;
    if (((kw >> ((i + 1) & 63)) & 1ull) && tid < 16) keep &= ~cur;
  }
  for (int r = tid; r < 1024; r += 64) {
    unsigned long long wv = __shfl(keep, r >> 6);
    bool kp = (r < Kl) && ((wv >> (r & 63)) & 1ull);
    scnms[nl * 1024 + r] = kp ? selscore[nl * 1024 + r] : -1e9f;
  }
}

// ---------------- kernel 6: final per-image top-1000 of 4768 + output ----------------
DEVI float cand_score(const float* scnms, int n, int g) {
  int l = g / 1000;               // g < 4768 -> l in [0,4]
  int r = g - l * 1000;
  return scnms[((n * 5 + l) << 10) + r];
}

__global__ __launch_bounds__(1024) void final_topk(
    const float* __restrict__ scnms, const float* __restrict__ selbox,
    float* __restrict__ out)
{
  const int tid = threadIdx.x;
  const int n = blockIdx.x;
  const int S = 4768;

  __shared__ unsigned hist[256];
  __shared__ unsigned sh_prefix, sh_need, s_base, s_cb;
  __shared__ unsigned waveTot[16], waveOff[16];
  __shared__ unsigned long long sortbuf[1024];

  unsigned prefix = 0, need = 1000;
  for (int p = 0; p < 4; ++p) {
    for (int i = tid; i < 256; i += 1024) hist[i] = 0;
    __syncthreads();
    const int shift = 24 - p * 8;
    for (int i = tid; i < S; i += 1024) {
      unsigned k = key_of(cand_score(scnms, n, i));
      if (p == 0 || (k >> (shift + 8)) == prefix)
        atomicAdd(&hist[(k >> shift) & 255u], 1u);
    }
    __syncthreads();
    if (tid == 0) {
      unsigned cum = 0;
      for (int b = 255; b >= 0; --b) {
        unsigned c = hist[b];
        if (cum + c >= need) { sh_prefix = (prefix << 8) | (unsigned)b; sh_need = need - cum; break; }
        cum += c;
      }
    }
    __syncthreads();
    prefix = sh_prefix; need = sh_need;
    __syncthreads();
  }
  const unsigned Tkey = prefix;

  if (tid == 0) s_base = 0;
  __syncthreads();
  for (int pass = 0; pass < 2; ++pass) {
    for (int st = 0; st < S; st += 1024) {
      const int i = st + tid;
      bool flag = false; unsigned k = 0;
      if (i < S) {
        k = key_of(cand_score(scnms, n, i));
        flag = (pass == 0) ? (k > Tkey) : (k == Tkey);
      }
      unsigned long long m = __ballot(flag);
      const int lane = tid & 63, w = tid >> 6;
      unsigned mypre = (unsigned)__popcll(m & ((1ull << lane) - 1ull));
      if (lane == 0) waveTot[w] = (unsigned)__popcll(m);
      __syncthreads();
      if (tid == 0) {
        unsigned ss = 0;
        for (int q = 0; q < 16; ++q) { waveOff[q] = ss; ss += waveTot[q]; }
        s_cb = s_base; s_base += ss;
      }
      __syncthreads();
      if (flag) {
        unsigned pos = s_cb + waveOff[w] + mypre;
        if (pos < 1000u)
          sortbuf[pos] = (((unsigned long long)k) << 32) |
                         (unsigned long long)(0xFFFFFFFFu - (unsigned)i);
      }
      __syncthreads();
    }
  }
  if (tid >= 1000) sortbuf[tid] = (unsigned long long)(0xFFFFFFFFu - (unsigned)tid);
  __syncthreads();

  for (int k2 = 2; k2 <= 1024; k2 <<= 1) {
    for (int j = k2 >> 1; j > 0; j >>= 1) {
      const int i = tid, ixj = i ^ j;
      if (ixj > i) {
        unsigned long long a = sortbuf[i], b = sortbuf[ixj];
        const bool desc = (i & k2) == 0;
        if (desc ? (a < b) : (a > b)) { sortbuf[i] = b; sortbuf[ixj] = a; }
      }
      __syncthreads();
    }
  }

  if (tid < 1000) {
    unsigned long long v = sortbuf[tid];
    unsigned k = (unsigned)(v >> 32);
    int g = (int)(0xFFFFFFFFu - (unsigned)(v & 0xFFFFFFFFull));
    int l = g / 1000, r = g - l * 1000;
    const float* b = selbox + ((size_t)((n * 5 + l) * 1024 + r)) * 4;
    size_t ob_ = ((size_t)n * 1000 + tid) * 4;
    out[ob_ + 0] = b[0]; out[ob_ + 1] = b[1];
    out[ob_ + 2] = b[2]; out[ob_ + 3] = b[3];
    out[8000 + n * 1000 + tid] = key_dec(k);
  }
}

// ---------------- host launcher ----------------
extern "C" void kernel_launch(void* const* d_in, const int* in_sizes, int n_in,
                              void* d_out, int out_size, void* d_ws, size_t ws_size,
                              hipStream_t stream)
{
  const float* feats[5];
  for (int i = 0; i < 5; ++i) feats[i] = (const float*)d_in[i];
  const float* conv_w  = (const float*)d_in[5];
  const float* conv_b  = (const float*)d_in[6];
  const float* obj_w   = (const float*)d_in[7];
  const float* obj_b   = (const float*)d_in[8];
  const float* delta_w = (const float*)d_in[9];
  const float* delta_b = (const float*)d_in[10];

  char* wsp = (char*)d_ws;
  float* wT       = (float*)wsp;  wsp += (size_t)2304 * 256 * 4;     // 2.36 MB
  float* logits   = (float*)wsp;  wsp += (size_t)NIMG * S_TOT * 4;   // 2.10 MB
  float* deltas   = (float*)wsp;  wsp += (size_t)NIMG * S_TOT * 16;  // 8.38 MB
  float* selscore = (float*)wsp;  wsp += (size_t)10 * 1024 * 4;
  float* selbox   = (float*)wsp;  wsp += (size_t)10 * 1024 * 16;
  unsigned* selvalid = (unsigned*)wsp; wsp += (size_t)10 * 1024 * 4;
  float* scnms    = (float*)wsp;  wsp += (size_t)10 * 1024 * 4;
  unsigned long long* sup = (unsigned long long*)wsp;
  wsp += (size_t)10 * 1024 * 16 * 8;                                 // 1.31 MB

  transpose_w<<<dim3(2304), dim3(256), 0, stream>>>(conv_w, wT);

  static const int hH[5]    = {256, 128, 64, 32, 16};
  static const int hloff[5] = {0, 196608, 245760, 258048, 261120};
  for (int l = 0; l < 5; ++l) {
    int H = hH[l], W = hH[l];
    dim3 grid((W / 16) * (H / 4), NIMG);
    conv_fused<<<grid, dim3(512), 0, stream>>>(
        feats[l], wT, conv_b, obj_w, obj_b, delta_w, delta_b,
        logits, deltas, H, W, hloff[l]);
  }
  topk_kernel<<<dim3(10), dim3(1024), 0, stream>>>(logits, deltas,
                                                   selscore, selbox, selvalid);
  nms_sup<<<dim3(640), dim3(256), 0, stream>>>(selbox, sup);
  nms_reduce<<<dim3(10), dim3(64), 0, stream>>>(selvalid, sup, selscore, scnms);
  final_topk<<<dim3(NIMG), dim3(1024), 0, stream>>>(scnms, selbox, (float*)d_out);
}

// Round 2
// 3503.846 us; speedup vs baseline: 1.3041x; 1.3041x over previous
//
#include <hip/hip_runtime.h>
#include <stdint.h>

#define DEVI __device__ __forceinline__

#define S_TOT 261888
#define NIMG  2
#define SCLD  4.135166556742356   // log(1000/16)

// ---------------- constant tables (all compile-time) ----------------
__constant__ int    c_S[5]    = {196608, 49152, 12288, 3072, 768};
__constant__ int    c_loff[5] = {0, 196608, 245760, 258048, 261120};
__constant__ int    c_K[5]    = {1000, 1000, 1000, 1000, 768};
__constant__ int    c_Wl[5]   = {256, 128, 64, 32, 16};
__constant__ int    c_str[5]  = {4, 8, 16, 32, 64};
__constant__ double c_sz[5]   = {32.0, 64.0, 128.0, 256.0, 512.0};
__constant__ double c_rat[3]  = {0.5, 1.0, 2.0};
// merged conv block decode: tiles are 16x8 px; per-level block counts {512,128,32,8,2}
__constant__ int    c_boff[6] = {0, 512, 640, 672, 680, 682};
__constant__ int    c_Hl[5]   = {256, 128, 64, 32, 16};

// order-preserving float<->uint key (ascending key == ascending float)
DEVI unsigned key_of(float f) {
  unsigned u = __float_as_uint(f);
  return (u & 0x80000000u) ? ~u : (u | 0x80000000u);
}
DEVI float key_dec(unsigned k) {
  unsigned u = (k & 0x80000000u) ? (k & 0x7fffffffu) : ~k;
  return __uint_as_float(u);
}

// ---------------- kernel 1: weight relayout w[co][ci*9+j] -> wT2[(ci*8+cob)*288 + j*32 + i] ----------------
// gives each (wave=cob, input-channel=ci) a CONTIGUOUS 288-dword run for s_load_dwordx16
__global__ void transpose_w(const float* __restrict__ w, float* __restrict__ wT2) {
  int k  = blockIdx.x;   // 0..2303  (ci*9 + j)
  int co = threadIdx.x;  // 0..255
  int ci = k / 9, j = k - ci * 9;
  wT2[((size_t)(ci * 8 + (co >> 5))) * 288 + j * 32 + (co & 31)] = w[co * 2304 + k];
}

// ---------------- kernel 2: fused conv3x3+bias+relu then 1x1 obj/delta, ALL levels in one grid ----
// block = 512 thr (8 waves). tile = 16x8 px, lane owns 2 px (py, py+4); wave w owns cout [32w,32w+32)
__global__ __launch_bounds__(512, 4) void conv_fused(
    const float* __restrict__ x0, const float* __restrict__ x1,
    const float* __restrict__ x2, const float* __restrict__ x3,
    const float* __restrict__ x4,
    const float* __restrict__ wT2,
    const float* __restrict__ cb, const float* __restrict__ ow,
    const float* __restrict__ ob, const float* __restrict__ dwt,
    const float* __restrict__ db, float* __restrict__ logits,
    float* __restrict__ deltas)
{
  __shared__ float lds[7680];   // 30 KB: patch (5760 floats) / reduce buf (7680)
  const int tid = threadIdx.x;
  const int n = blockIdx.y;
  const int b = blockIdx.x;
  int l = 0;
#pragma unroll
  for (int q = 1; q < 5; ++q) if (b >= c_boff[q]) l = q;
  const int t = b - c_boff[l];
  const int H = c_Hl[l], W = H;
  const int tx = t & ((16 >> l) - 1), ty = t >> (4 - l);
  const int px0 = tx << 4, py0t = ty << 3;
  const int loff = c_loff[l];
  const float* xin = (l == 0) ? x0 : (l == 1) ? x1 : (l == 2) ? x2 : (l == 3) ? x3 : x4;
  xin += (size_t)n * 256 * H * W;

  const int lane = tid & 63, wv = tid >> 6;
  const int px = lane & 15, py = lane >> 4;   // py 0..3
  const int cob = __builtin_amdgcn_readfirstlane(wv);   // wave-uniform -> s_load path
  const int co0 = cob << 5;

  float a0[32], a1[32];
#pragma unroll
  for (int i = 0; i < 32; ++i) { a0[i] = 0.f; a1[i] = 0.f; }

  for (int ch = 0; ch < 8; ++ch) {          // 8 chunks of 32 input channels
    const int ci0 = ch << 5;
    __syncthreads();
    // stage input patch 32ci x 10 x 18 (zero-padded halo)
    for (int tt = tid; tt < 32 * 180; tt += 512) {
      int ci = tt / 180, rem = tt % 180;
      int ry = rem / 18, rx = rem % 18;
      int gy = py0t + ry - 1, gx = px0 + rx - 1;
      float v = 0.f;
      if (gy >= 0 && gy < H && gx >= 0 && gx < W)
        v = xin[((size_t)(ci0 + ci) * H + gy) * W + gx];
      lds[tt] = v;
    }
    __syncthreads();
#pragma unroll 1
    for (int cc = 0; cc < 32; ++cc) {
      const int pb = cc * 180 + py * 18 + px;
      float pv0[9], pv1[9];
#pragma unroll
      for (int ky = 0; ky < 3; ++ky)
#pragma unroll
        for (int kx = 0; kx < 3; ++kx) {
          pv0[ky * 3 + kx] = lds[pb + ky * 18 + kx];
          pv1[ky * 3 + kx] = lds[pb + (ky + 4) * 18 + kx];
        }
      const float* wr = wT2 + ((size_t)((ci0 + cc) * 8 + cob)) * 288;  // uniform, contiguous 288
#pragma unroll
      for (int j = 0; j < 9; ++j) {
#pragma unroll
        for (int i = 0; i < 32; ++i) {
          const float wgt = wr[j * 32 + i];
          a0[i] = fmaf(wgt, pv0[j], a0[i]);
          a1[i] = fmaf(wgt, pv1[j], a1[i]);
        }
      }
    }
  }

  // epilogue: bias+relu + partial 1x1 convs (3 obj + 12 delta), two pixel-halves (rows 0-3, 4-7)
#pragma unroll
  for (int h = 0; h < 2; ++h) {
    float part[15];
#pragma unroll
    for (int f = 0; f < 15; ++f) part[f] = 0.f;
#pragma unroll
    for (int i = 0; i < 32; ++i) {
      float v = (h ? a1[i] : a0[i]) + cb[co0 + i];
      float tv = fmaxf(v, 0.f);
#pragma unroll
      for (int f = 0; f < 3; ++f)  part[f]     = fmaf(tv, ow[f * 256 + co0 + i],  part[f]);
#pragma unroll
      for (int f = 0; f < 12; ++f) part[3 + f] = fmaf(tv, dwt[f * 256 + co0 + i], part[3 + f]);
    }
    __syncthreads();
#pragma unroll
    for (int f = 0; f < 15; ++f) lds[wv * 960 + f * 64 + lane] = part[f];
    __syncthreads();
    for (int tt = tid; tt < 960; tt += 512) {
      float s = 0.f;
#pragma unroll
      for (int w2 = 0; w2 < 8; ++w2) s += lds[w2 * 960 + tt];   // fixed order: deterministic
      int f = tt >> 6, p = tt & 63;
      int gx = px0 + (p & 15), gy = py0t + (p >> 4) + 4 * h;
      int cell = gy * W + gx;
      if (f < 3) {
        logits[(size_t)n * S_TOT + loff + cell * 3 + f] = s + ob[f];
      } else {
        int chn = f - 3, a = chn >> 2, c = chn & 3;
        deltas[(((size_t)n * S_TOT + loff + cell * 3 + a) << 2) + c] = s + db[chn];
      }
    }
  }
}

// ---------------- kernel 3: exact top-K + box decode per (image, level) ----------------
__global__ __launch_bounds__(1024) void topk_kernel(
    const float* __restrict__ logits, const float* __restrict__ deltas,
    float* __restrict__ selscore, float* __restrict__ selbox,
    unsigned* __restrict__ selvalid)
{
  const int tid = threadIdx.x;
  const int nl = blockIdx.x, n = nl / 5, l = nl % 5;
  const int Sl = c_S[l], loff = c_loff[l], Kl = c_K[l], Wl = c_Wl[l], strl = c_str[l];
  const float* sc = logits + (size_t)n * S_TOT + loff;

  __shared__ unsigned hist[256];
  __shared__ unsigned sh_prefix, sh_need, s_base, s_cb;
  __shared__ unsigned waveTot[16], waveOff[16];
  __shared__ unsigned long long sortbuf[1024];

  // phase 1: 4-pass radix histogram -> exact Kl-th largest key
  unsigned prefix = 0, need = (unsigned)Kl;
  for (int p = 0; p < 4; ++p) {
    for (int i = tid; i < 256; i += 1024) hist[i] = 0;
    __syncthreads();
    const int shift = 24 - p * 8;
    for (int i = tid; i < Sl; i += 1024) {
      unsigned k = key_of(sc[i]);
      if (p == 0 || (k >> (shift + 8)) == prefix)
        atomicAdd(&hist[(k >> shift) & 255u], 1u);
    }
    __syncthreads();
    if (tid == 0) {
      unsigned cum = 0;
      for (int b = 255; b >= 0; --b) {
        unsigned c = hist[b];
        if (cum + c >= need) { sh_prefix = (prefix << 8) | (unsigned)b; sh_need = need - cum; break; }
        cum += c;
      }
    }
    __syncthreads();
    prefix = sh_prefix; need = sh_need;
    __syncthreads();
  }
  const unsigned Tkey = prefix;

  // phase 2: stable compaction (strictly-greater, then equals capped) -> exactly Kl entries
  if (tid == 0) s_base = 0;
  __syncthreads();
  for (int pass = 0; pass < 2; ++pass) {
    for (int st = 0; st < Sl; st += 1024) {
      const int i = st + tid;
      bool flag = false; unsigned k = 0;
      if (i < Sl) {
        k = key_of(sc[i]);
        flag = (pass == 0) ? (k > Tkey) : (k == Tkey);
      }
      unsigned long long m = __ballot(flag);
      const int lane = tid & 63, w = tid >> 6;
      unsigned mypre = (unsigned)__popcll(m & ((1ull << lane) - 1ull));
      if (lane == 0) waveTot[w] = (unsigned)__popcll(m);
      __syncthreads();
      if (tid == 0) {
        unsigned ss = 0;
        for (int q = 0; q < 16; ++q) { waveOff[q] = ss; ss += waveTot[q]; }
        s_cb = s_base; s_base += ss;
      }
      __syncthreads();
      if (flag) {
        unsigned pos = s_cb + waveOff[w] + mypre;
        if (pos < (unsigned)Kl)
          sortbuf[pos] = (((unsigned long long)k) << 32) |
                         (unsigned long long)(0xFFFFFFFFu - (unsigned)i);
      }
      __syncthreads();
    }
  }
  if (tid >= Kl) sortbuf[tid] = (unsigned long long)(0xFFFFFFFFu - (unsigned)tid); // pads: key 0
  __syncthreads();

  // phase 3: bitonic sort of 1024 u64, descending (key desc, idx asc via ~idx)
  for (int k2 = 2; k2 <= 1024; k2 <<= 1) {
    for (int j = k2 >> 1; j > 0; j >>= 1) {
      const int i = tid, ixj = i ^ j;
      if (ixj > i) {
        unsigned long long a = sortbuf[i], b = sortbuf[ixj];
        const bool desc = (i & k2) == 0;
        if (desc ? (a < b) : (a > b)) { sortbuf[i] = b; sortbuf[ixj] = a; }
      }
      __syncthreads();
    }
  }

  // phase 4: decode boxes (anchors in f64 to bit-match np reference)
  const int r = tid;
  const int o = nl * 1024 + r;
  if (r < Kl) {
    unsigned long long v = sortbuf[r];
    unsigned k = (unsigned)(v >> 32);
    unsigned ai = 0xFFFFFFFFu - (unsigned)(v & 0xFFFFFFFFull);
    float score = key_dec(k);
    int cell = (int)(ai / 3u), a = (int)(ai % 3u);
    int xg = cell % Wl, yg = cell / Wl;
    double rr = c_rat[a], sz = c_sz[l];
    double wsd = sqrt(sz * sz / rr);
    double hw = 0.5 * wsd, hh = 0.5 * wsd * rr;
    double xs = (double)(xg * strl), ys = (double)(yg * strl);
    float a0 = (float)(xs - hw), a1 = (float)(ys - hh);
    float a2 = (float)(xs + hw), a3 = (float)(ys + hh);
    const float* dp = deltas + (((size_t)n * S_TOT + loff + ai) << 2);
    float dx = dp[0], dy = dp[1], dw_ = dp[2], dh_ = dp[3];
    float aw = a2 - a0, ah = a3 - a1;
    float cx = a0 + 0.5f * aw, cy = a1 + 0.5f * ah;
    dw_ = fminf(dw_, (float)SCLD); dh_ = fminf(dh_, (float)SCLD);
    float pcx = dx * aw + cx, pcy = dy * ah + cy;
    float pw = expf(dw_) * aw, ph = expf(dh_) * ah;
    float b0 = fminf(fmaxf(pcx - 0.5f * pw, 0.f), 1024.f);
    float b1 = fminf(fmaxf(pcy - 0.5f * ph, 0.f), 1024.f);
    float b2 = fminf(fmaxf(pcx + 0.5f * pw, 0.f), 1024.f);
    float b3 = fminf(fmaxf(pcy + 0.5f * ph, 0.f), 1024.f);
    unsigned valid = ((b2 - b0) > 0.f && (b3 - b1) > 0.f) ? 1u : 0u;
    selscore[o] = score;
    selbox[o * 4 + 0] = b0; selbox[o * 4 + 1] = b1;
    selbox[o * 4 + 2] = b2; selbox[o * 4 + 3] = b3;
    selvalid[o] = valid;
  } else {
    selscore[o] = -1e9f;
    selbox[o * 4 + 0] = 0.f; selbox[o * 4 + 1] = 0.f;
    selbox[o * 4 + 2] = 0.f; selbox[o * 4 + 3] = 0.f;
    selvalid[o] = 0u;
  }
}

// ---------------- kernel 4: NMS suppression bitmask matrix ----------------
__global__ __launch_bounds__(256) void nms_sup(
    const float* __restrict__ selbox, unsigned long long* __restrict__ sup)
{
  int gid = blockIdx.x * 256 + threadIdx.x;  // 10 * 1024 * 16
  int w = gid & 15, i = (gid >> 4) & 1023, nl = gid >> 14;
  if (nl >= 10) return;
  int l = nl % 5, Kl = c_K[l];
  unsigned long long bits = 0;
  if (i < Kl) {
    const float* bi = selbox + (size_t)(nl * 1024 + i) * 4;
    float x0 = bi[0], y0 = bi[1], x1 = bi[2], y1 = bi[3];
    float ar = (x1 - x0) * (y1 - y0);
    int jlo = w * 64; if (jlo < i + 1) jlo = i + 1;
    int jhi = w * 64 + 64; if (jhi > Kl) jhi = Kl;
    for (int j = jlo; j < jhi; ++j) {
      const float* bj = selbox + (size_t)(nl * 1024 + j) * 4;
      float u0 = fmaxf(x0, bj[0]), v0 = fmaxf(y0, bj[1]);
      float u1 = fminf(x1, bj[2]), v1 = fminf(y1, bj[3]);
      float iw = fmaxf(u1 - u0, 0.f), ih = fmaxf(v1 - v0, 0.f);
      float inter = iw * ih;
      float aj = (bj[2] - bj[0]) * (bj[3] - bj[1]);
      float iou = inter / fmaxf(ar + aj - inter, 1e-9f);
      if (iou > 0.7f) bits |= 1ull << (j - w * 64);
    }
  }
  sup[(size_t)(nl * 1024 + i) * 16 + w] = bits;
}

// ---------------- kernel 5: sequential greedy NMS reduce (1 wave / (n,l)) ----------------
__global__ __launch_bounds__(64) void nms_reduce(
    const unsigned* __restrict__ selvalid, const unsigned long long* __restrict__ sup,
    const float* __restrict__ selscore, float* __restrict__ scnms)
{
  const int nl = blockIdx.x, tid = threadIdx.x;
  const int l = nl % 5, Kl = c_K[l];
  unsigned long long keep = 0;
  if (tid < 16) {
    for (int t = 0; t < 64; ++t) {
      int r = tid * 64 + t;
      if (r < Kl && selvalid[nl * 1024 + r]) keep |= 1ull << t;
    }
  }
  const unsigned long long* srow = sup + (size_t)nl * 1024 * 16;
  unsigned long long rowA = (tid < 16) ? srow[(size_t)0 * 16 + tid] : 0;
  unsigned long long rowB = (tid < 16 && Kl > 1) ? srow[(size_t)1 * 16 + tid] : 0;
  for (int i = 0; i < Kl; i += 2) {   // Kl is even (1000 / 768)
    unsigned long long kw = __shfl(keep, i >> 6);
    unsigned long long cur = rowA;
    rowA = (tid < 16 && i + 2 < Kl) ? srow[(size_t)(i + 2) * 16 + tid] : 0;
    if (((kw >> (i & 63)) & 1ull) && tid < 16) keep &= ~cur;
    kw = __shfl(keep, (i + 1) >> 6);
    cur = rowB;
    rowB = (tid < 16 && i + 3 < Kl) ? srow[(size_t)(i + 3) * 16 + tid] : 0;
    if (((kw >> ((i + 1) & 63)) & 1ull) && tid < 16) keep &= ~cur;
  }
  for (int r = tid; r < 1024; r += 64) {
    unsigned long long wv = __shfl(keep, r >> 6);
    bool kp = (r < Kl) && ((wv >> (r & 63)) & 1ull);
    scnms[nl * 1024 + r] = kp ? selscore[nl * 1024 + r] : -1e9f;
  }
}

// ---------------- kernel 6: final per-image top-1000 of 4768 + output ----------------
DEVI float cand_score(const float* scnms, int n, int g) {
  int l = g / 1000;               // g < 4768 -> l in [0,4]
  int r = g - l * 1000;
  return scnms[((n * 5 + l) << 10) + r];
}

__global__ __launch_bounds__(1024) void final_topk(
    const float* __restrict__ scnms, const float* __restrict__ selbox,
    float* __restrict__ out)
{
  const int tid = threadIdx.x;
  const int n = blockIdx.x;
  const int S = 4768;

  __shared__ unsigned hist[256];
  __shared__ unsigned sh_prefix, sh_need, s_base, s_cb;
  __shared__ unsigned waveTot[16], waveOff[16];
  __shared__ unsigned long long sortbuf[1024];

  unsigned prefix = 0, need = 1000;
  for (int p = 0; p < 4; ++p) {
    for (int i = tid; i < 256; i += 1024) hist[i] = 0;
    __syncthreads();
    const int shift = 24 - p * 8;
    for (int i = tid; i < S; i += 1024) {
      unsigned k = key_of(cand_score(scnms, n, i));
      if (p == 0 || (k >> (shift + 8)) == prefix)
        atomicAdd(&hist[(k >> shift) & 255u], 1u);
    }
    __syncthreads();
    if (tid == 0) {
      unsigned cum = 0;
      for (int b = 255; b >= 0; --b) {
        unsigned c = hist[b];
        if (cum + c >= need) { sh_prefix = (prefix << 8) | (unsigned)b; sh_need = need - cum; break; }
        cum += c;
      }
    }
    __syncthreads();
    prefix = sh_prefix; need = sh_need;
    __syncthreads();
  }
  const unsigned Tkey = prefix;

  if (tid == 0) s_base = 0;
  __syncthreads();
  for (int pass = 0; pass < 2; ++pass) {
    for (int st = 0; st < S; st += 1024) {
      const int i = st + tid;
      bool flag = false; unsigned k = 0;
      if (i < S) {
        k = key_of(cand_score(scnms, n, i));
        flag = (pass == 0) ? (k > Tkey) : (k == Tkey);
      }
      unsigned long long m = __ballot(flag);
      const int lane = tid & 63, w = tid >> 6;
      unsigned mypre = (unsigned)__popcll(m & ((1ull << lane) - 1ull));
      if (lane == 0) waveTot[w] = (unsigned)__popcll(m);
      __syncthreads();
      if (tid == 0) {
        unsigned ss = 0;
        for (int q = 0; q < 16; ++q) { waveOff[q] = ss; ss += waveTot[q]; }
        s_cb = s_base; s_base += ss;
      }
      __syncthreads();
      if (flag) {
        unsigned pos = s_cb + waveOff[w] + mypre;
        if (pos < 1000u)
          sortbuf[pos] = (((unsigned long long)k) << 32) |
                         (unsigned long long)(0xFFFFFFFFu - (unsigned)i);
      }
      __syncthreads();
    }
  }
  if (tid >= 1000) sortbuf[tid] = (unsigned long long)(0xFFFFFFFFu - (unsigned)tid);
  __syncthreads();

  for (int k2 = 2; k2 <= 1024; k2 <<= 1) {
    for (int j = k2 >> 1; j > 0; j >>= 1) {
      const int i = tid, ixj = i ^ j;
      if (ixj > i) {
        unsigned long long a = sortbuf[i], b = sortbuf[ixj];
        const bool desc = (i & k2) == 0;
        if (desc ? (a < b) : (a > b)) { sortbuf[i] = b; sortbuf[ixj] = a; }
      }
      __syncthreads();
    }
  }

  if (tid < 1000) {
    unsigned long long v = sortbuf[tid];
    unsigned k = (unsigned)(v >> 32);
    int g = (int)(0xFFFFFFFFu - (unsigned)(v & 0xFFFFFFFFull));
    int l = g / 1000, r = g - l * 1000;
    const float* b = selbox + ((size_t)((n * 5 + l) * 1024 + r)) * 4;
    size_t ob_ = ((size_t)n * 1000 + tid) * 4;
    out[ob_ + 0] = b[0]; out[ob_ + 1] = b[1];
    out[ob_ + 2] = b[2]; out[ob_ + 3] = b[3];
    out[8000 + n * 1000 + tid] = key_dec(k);
  }
}

// ---------------- host launcher ----------------
extern "C" void kernel_launch(void* const* d_in, const int* in_sizes, int n_in,
                              void* d_out, int out_size, void* d_ws, size_t ws_size,
                              hipStream_t stream)
{
  const float* feats[5];
  for (int i = 0; i < 5; ++i) feats[i] = (const float*)d_in[i];
  const float* conv_w  = (const float*)d_in[5];
  const float* conv_b  = (const float*)d_in[6];
  const float* obj_w   = (const float*)d_in[7];
  const float* obj_b   = (const float*)d_in[8];
  const float* delta_w = (const float*)d_in[9];
  const float* delta_b = (const float*)d_in[10];

  char* wsp = (char*)d_ws;
  float* wT2      = (float*)wsp;  wsp += (size_t)2304 * 256 * 4;     // 2.36 MB
  float* logits   = (float*)wsp;  wsp += (size_t)NIMG * S_TOT * 4;   // 2.10 MB
  float* deltas   = (float*)wsp;  wsp += (size_t)NIMG * S_TOT * 16;  // 8.38 MB
  float* selscore = (float*)wsp;  wsp += (size_t)10 * 1024 * 4;
  float* selbox   = (float*)wsp;  wsp += (size_t)10 * 1024 * 16;
  unsigned* selvalid = (unsigned*)wsp; wsp += (size_t)10 * 1024 * 4;
  float* scnms    = (float*)wsp;  wsp += (size_t)10 * 1024 * 4;
  unsigned long long* sup = (unsigned long long*)wsp;
  wsp += (size_t)10 * 1024 * 16 * 8;                                 // 1.31 MB

  transpose_w<<<dim3(2304), dim3(256), 0, stream>>>(conv_w, wT2);

  conv_fused<<<dim3(682, NIMG), dim3(512), 0, stream>>>(
      feats[0], feats[1], feats[2], feats[3], feats[4],
      wT2, conv_b, obj_w, obj_b, delta_w, delta_b, logits, deltas);

  topk_kernel<<<dim3(10), dim3(1024), 0, stream>>>(logits, deltas,
                                                   selscore, selbox, selvalid);
  nms_sup<<<dim3(640), dim3(256), 0, stream>>>(selbox, sup);
  nms_reduce<<<dim3(10), dim3(64), 0, stream>>>(selvalid, sup, selscore, scnms);
  final_topk<<<dim3(NIMG), dim3(1024), 0, stream>>>(scnms, selbox, (float*)d_out);
}